// Round 1
// baseline (74296.545 us; speedup 1.0000x reference)
//
#include <hip/hip_runtime.h>
#include <hip/hip_cooperative_groups.h>

namespace cg = cooperative_groups;

constexpr int B_ = 128, T_ = 1024, D_ = 512, U_ = 512;
constexpr int NBLK = 256, NTHR = 1024;
constexpr int G4 = 4 * U_;   // 2048 gate columns

__device__ __forceinline__ float sigm(float v) { return 1.0f / (1.0f + expf(-v)); }

// 256 blocks (one per CU), each owns 2 u-indices -> 8 gate columns.
// Weights for those columns live in LDS for the whole T loop.
// One cooperative grid sync per step; h double-buffered in ws; c,ut in LDS.
__global__ __launch_bounds__(NTHR, 4) void skiplstm_kernel(
    const float* __restrict__ x, const float* __restrict__ wk,
    const float* __restrict__ wr, const float* __restrict__ bias,
    const float* __restrict__ dk, const float* __restrict__ dbp,
    float* __restrict__ out, float* __restrict__ hbuf, float* __restrict__ pd)
{
    __shared__ __align__(16) float Wlds[8][1024];   // [col][K]  K = [x(512); h(512)]
    __shared__ float parts[8][128][9];              // [ksub][b][col] (+pad)
    __shared__ float c_state[128][2];               // cell state for our 2 u's
    __shared__ float ut_lds[128];                   // per-batch skip state (replicated per block)
    __shared__ float bias_l[8];
    __shared__ float dk_l[4];                       // dk[u0+j], dk[U+u0+j]
    __shared__ float db_l;

    const int tid = threadIdx.x;
    const int u0 = blockIdx.x * 2;

    // --- one-time staging: weight slice (columns g*512+u0+j for g=0..3, j=0..1) ---
    #pragma unroll
    for (int c = 0; c < 8; ++c) {
        const int g = c >> 1, j = c & 1;
        const int gcol = g * U_ + u0 + j;
        Wlds[c][tid] = (tid < D_) ? wk[(size_t)tid * G4 + gcol]
                                  : wr[(size_t)(tid - D_) * G4 + gcol];
    }
    if (tid < 8)  bias_l[tid] = bias[(tid >> 1) * U_ + u0 + (tid & 1)];
    if (tid < 2) { dk_l[tid] = dk[u0 + tid]; dk_l[2 + tid] = dk[U_ + u0 + tid]; }
    if (tid == 0) db_l = dbp[0];
    if (tid < 128) { ut_lds[tid] = 1.0f; c_state[tid][0] = 0.0f; c_state[tid][1] = 0.0f; }
    // zero both h buffers (2*128*512 floats spread over 256 blocks * 512 threads)
    if (tid < 512) hbuf[blockIdx.x * 512 + tid] = 0.0f;

    cg::grid_group grid = cg::this_grid();
    __syncthreads();
    grid.sync();

    const int b    = tid & 127;   // batch row this thread accumulates for
    const int ksub = tid >> 7;    // 0..7 : K-range [ksub*128, ksub*128+128)

    #pragma unroll 1
    for (int t = 0; t < T_; ++t) {
        const float* __restrict__ hcur = hbuf + (t & 1) * (B_ * U_);
        float* __restrict__ hnxt = hbuf + ((t + 1) & 1) * (B_ * U_);

        // ---- phase 1a: GEMM partials (8 cols x 128 K per thread) ----
        const float* inp = (ksub < 4)
            ? (x + (size_t)b * (T_ * D_) + (size_t)t * D_ + ksub * 128)
            : (hcur + b * U_ + (ksub - 4) * 128);
        const float4* __restrict__ in4 = (const float4*)inp;
        const int kb4 = ksub * 32;

        float acc[8] = {0.f,0.f,0.f,0.f,0.f,0.f,0.f,0.f};
        #pragma unroll 1
        for (int l = 0; l < 8; ++l) {
            float4 v[4];                 // 64 B = one cache line per lane
            #pragma unroll
            for (int m = 0; m < 4; ++m) v[m] = in4[l*4 + m];
            #pragma unroll
            for (int c = 0; c < 8; ++c) {
                const float4* wrow = (const float4*)(&Wlds[c][0]);
                #pragma unroll
                for (int m = 0; m < 4; ++m) {
                    const float4 w = wrow[kb4 + l*4 + m];
                    acc[c] += v[m].x*w.x + v[m].y*w.y + v[m].z*w.z + v[m].w*w.w;
                }
            }
        }
        #pragma unroll
        for (int c = 0; c < 8; ++c) parts[ksub][b][c] = acc[c];
        __syncthreads();

        // ---- phase 1b: gates, state blend, output, dense partial ----
        if (tid < 256) {
            const int bb = tid >> 1, j = tid & 1;
            float z[4];
            #pragma unroll
            for (int g = 0; g < 4; ++g) {
                float s = bias_l[g*2 + j];
                #pragma unroll
                for (int ks = 0; ks < 8; ++ks) s += parts[ks][bb][g*2 + j];
                z[g] = s;
            }
            const float ut    = ut_lds[bb];
            const float ug    = rintf(ut);          // exactly 0.0 or 1.0 (half-to-even)
            const float c_old = c_state[bb][j];
            const float si = sigm(z[0]);
            const float sf = sigm(z[1]);
            const float gg = tanhf(z[2]);
            const float so = sigm(z[3]);
            const float c_n = sf * c_old + si * gg;
            const float h_n = so * tanhf(c_n);
            const float h_old = hcur[bb * U_ + u0 + j];
            const float hbv = ug * h_old + (1.f - ug) * h_n;
            const float cbv = ug * c_old + (1.f - ug) * c_n;
            out[(size_t)bb * (T_ * U_) + (size_t)t * U_ + u0 + j] = h_n;  // out is always h_n
            hnxt[bb * U_ + u0 + j] = hbv;
            c_state[bb][j] = cbv;
            float p = hbv * dk_l[j] + cbv * dk_l[2 + j];
            p += __shfl_xor(p, 1);                  // combine j=0,1 (adjacent lanes)
            if (j == 0) pd[(t & 1) * (NBLK * B_) + blockIdx.x * B_ + bb] = p;
        }

        grid.sync();

        // ---- phase 2: every block redundantly reduces delta, updates its ut copy ----
        {
            const int bb2 = tid >> 3, o = tid & 7;
            const float* __restrict__ pdt = pd + (t & 1) * (NBLK * B_);
            float s = 0.f;
            #pragma unroll 1
            for (int i = 0; i < 32; ++i) s += pdt[(o * 32 + i) * B_ + bb2];
            s += __shfl_xor(s, 1);
            s += __shfl_xor(s, 2);
            s += __shfl_xor(s, 4);
            if (o == 0) {
                const float delta = sigm(s + db_l);
                const float ut = ut_lds[bb2];
                const float ug = rintf(ut);
                ut_lds[bb2] = ug * delta + (1.f - ug) * (ut + fminf(delta, 1.f - ut));
            }
        }
        __syncthreads();
    }
}

extern "C" void kernel_launch(void* const* d_in, const int* in_sizes, int n_in,
                              void* d_out, int out_size, void* d_ws, size_t ws_size,
                              hipStream_t stream)
{
    (void)in_sizes; (void)n_in; (void)out_size; (void)ws_size;
    const float* x  = (const float*)d_in[0];
    const float* wk = (const float*)d_in[1];
    const float* wr = (const float*)d_in[2];
    const float* bs = (const float*)d_in[3];
    const float* dk = (const float*)d_in[4];
    const float* db = (const float*)d_in[5];
    float* out  = (float*)d_out;
    float* hbuf = (float*)d_ws;                       // 2*128*512 floats (512 KB)
    float* pd   = hbuf + 2 * B_ * U_;                 // 2*256*128 floats (256 KB)

    void* args[] = { (void*)&x, (void*)&wk, (void*)&wr, (void*)&bs, (void*)&dk, (void*)&db,
                     (void*)&out, (void*)&hbuf, (void*)&pd };
    hipLaunchCooperativeKernel(reinterpret_cast<void*>(skiplstm_kernel),
                               dim3(NBLK), dim3(NTHR), args, 0, stream);
}

// Round 2
// 55449.426 us; speedup vs baseline: 1.3399x; 1.3399x over previous
//
#include <hip/hip_runtime.h>
#include <hip/hip_cooperative_groups.h>

namespace cg = cooperative_groups;

constexpr int B_ = 128, T_ = 1024, D_ = 512, U_ = 512;
constexpr int NBLK = 256, NTHR = 1024;
constexpr int G4 = 4 * U_;   // 2048 gate columns

__device__ __forceinline__ float sigm(float v) { return 1.0f / (1.0f + expf(-v)); }

// ---------------- prologue: x[b][t][k] -> xT[t][k][b] (coalesced both sides) --------
__global__ __launch_bounds__(256) void transpose_x(const float* __restrict__ x,
                                                   float* __restrict__ xT)
{
    __shared__ float tile[32][33];
    const int tileId = blockIdx.x;          // 1024 t * 16 ktiles * 4 btiles = 65536
    const int bt = tileId & 3;
    const int kt = (tileId >> 2) & 15;
    const int t  = tileId >> 6;
    const int tx = threadIdx.x & 31;
    const int ty = threadIdx.x >> 5;        // 0..7
    #pragma unroll
    for (int r = 0; r < 4; ++r) {
        const int b = bt * 32 + ty + r * 8;
        const int k = kt * 32 + tx;
        tile[ty + r * 8][tx] = x[(size_t)b * (T_ * D_) + (size_t)t * D_ + k];
    }
    __syncthreads();
    #pragma unroll
    for (int r = 0; r < 4; ++r) {
        const int k = kt * 32 + ty + r * 8;
        const int b = bt * 32 + tx;
        xT[((size_t)t * D_ + k) * B_ + b] = tile[tx][ty + r * 8];
    }
}

// ---------------- main: transposed-input path --------------------------------------
// 256 blocks, block owns 2 u (8 gate cols). W slice in LDS (broadcast reads).
// inT[k][b]: lanes along b -> coalesced 256B loads. hT kept [u][b], double-buffered.
__global__ __launch_bounds__(NTHR, 4) void skiplstm_kernel_T(
    const float* __restrict__ xT, const float* __restrict__ wk,
    const float* __restrict__ wr, const float* __restrict__ bias,
    const float* __restrict__ dk, const float* __restrict__ dbp,
    float* __restrict__ out, float* __restrict__ hbuf, float* __restrict__ pd)
{
    __shared__ __align__(16) float Wlds[8][1024];   // [col][K]  K = [x(512); h(512)]
    __shared__ float parts[8][128][9];              // [ksub][b][col] (+pad)
    __shared__ float c_state[128][2];
    __shared__ float ut_lds[128];
    __shared__ float bias_l[8];
    __shared__ float dk_l[4];
    __shared__ float db_l;

    const int tid = threadIdx.x;
    const int u0 = blockIdx.x * 2;

    #pragma unroll
    for (int c = 0; c < 8; ++c) {
        const int g = c >> 1, j = c & 1;
        const int gcol = g * U_ + u0 + j;
        Wlds[c][tid] = (tid < D_) ? wk[(size_t)tid * G4 + gcol]
                                  : wr[(size_t)(tid - D_) * G4 + gcol];
    }
    if (tid < 8)  bias_l[tid] = bias[(tid >> 1) * U_ + u0 + (tid & 1)];
    if (tid < 2) { dk_l[tid] = dk[u0 + tid]; dk_l[2 + tid] = dk[U_ + u0 + tid]; }
    if (tid == 0) db_l = dbp[0];
    if (tid < 128) { ut_lds[tid] = 1.0f; c_state[tid][0] = 0.0f; c_state[tid][1] = 0.0f; }
    if (tid < 512) hbuf[blockIdx.x * 512 + tid] = 0.0f;   // zero both hT buffers

    cg::grid_group grid = cg::this_grid();
    __syncthreads();
    grid.sync();

    const int b    = tid & 127;   // lane dim = b  -> coalesced inT reads
    const int ksub = tid >> 7;    // 0..7 : K-range [ksub*128, ksub*128+128)

    #pragma unroll 1
    for (int t = 0; t < T_; ++t) {
        const float* __restrict__ hcurT = hbuf + (t & 1) * (U_ * B_);
        float* __restrict__ hnxtT = hbuf + ((t + 1) & 1) * (U_ * B_);

        // ---- phase 1a: GEMM partials; inT[k][b] coalesced along lanes ----
        const float* __restrict__ src = (ksub < 4)
            ? (xT + ((size_t)t * D_ + ksub * 128) * B_ + b)
            : (hcurT + (size_t)(ksub - 4) * 128 * B_ + b);

        float acc[8] = {0.f,0.f,0.f,0.f,0.f,0.f,0.f,0.f};
        #pragma unroll 2
        for (int kq = 0; kq < 32; ++kq) {
            const float v0 = src[(kq * 4 + 0) * B_];
            const float v1 = src[(kq * 4 + 1) * B_];
            const float v2 = src[(kq * 4 + 2) * B_];
            const float v3 = src[(kq * 4 + 3) * B_];
            const int k4 = ksub * 32 + kq;
            #pragma unroll
            for (int c = 0; c < 8; ++c) {
                const float4 w = ((const float4*)(&Wlds[c][0]))[k4];  // broadcast
                acc[c] += v0 * w.x + v1 * w.y + v2 * w.z + v3 * w.w;
            }
        }
        #pragma unroll
        for (int c = 0; c < 8; ++c) parts[ksub][b][c] = acc[c];
        __syncthreads();

        // ---- phase 1b: gates, blend, output, dense partial ----
        if (tid < 256) {
            const int bb = tid >> 1, j = tid & 1;
            float z[4];
            #pragma unroll
            for (int g = 0; g < 4; ++g) {
                float s = bias_l[g*2 + j];
                #pragma unroll
                for (int ks = 0; ks < 8; ++ks) s += parts[ks][bb][g*2 + j];
                z[g] = s;
            }
            const float ut    = ut_lds[bb];
            const float ug    = rintf(ut);
            const float c_old = c_state[bb][j];
            const float si = sigm(z[0]);
            const float sf = sigm(z[1]);
            const float gg = tanhf(z[2]);
            const float so = sigm(z[3]);
            const float c_n = sf * c_old + si * gg;
            const float h_n = so * tanhf(c_n);
            const float h_old = hcurT[(u0 + j) * B_ + bb];
            const float hbv = ug * h_old + (1.f - ug) * h_n;
            const float cbv = ug * c_old + (1.f - ug) * c_n;
            out[(size_t)bb * (T_ * U_) + (size_t)t * U_ + u0 + j] = h_n;
            hnxtT[(u0 + j) * B_ + bb] = hbv;
            c_state[bb][j] = cbv;
            float p = hbv * dk_l[j] + cbv * dk_l[2 + j];
            p += __shfl_xor(p, 1);
            if (j == 0) pd[(t & 1) * (NBLK * B_) + blockIdx.x * B_ + bb] = p;
        }

        grid.sync();

        // ---- phase 2: redundant delta reduce, update private ut ----
        {
            const int bb2 = tid >> 3, o = tid & 7;
            const float* __restrict__ pdt = pd + (t & 1) * (NBLK * B_);
            float s = 0.f;
            #pragma unroll 1
            for (int i = 0; i < 32; ++i) s += pdt[(o * 32 + i) * B_ + bb2];
            s += __shfl_xor(s, 1);
            s += __shfl_xor(s, 2);
            s += __shfl_xor(s, 4);
            if (o == 0) {
                const float delta = sigm(s + db_l);
                const float ut = ut_lds[bb2];
                const float ug = rintf(ut);
                ut_lds[bb2] = ug * delta + (1.f - ug) * (ut + fminf(delta, 1.f - ut));
            }
        }
        __syncthreads();
    }
}

// ---------------- fallback: round-1 kernel (used if ws too small for xT) -----------
__global__ __launch_bounds__(NTHR, 4) void skiplstm_fallback(
    const float* __restrict__ x, const float* __restrict__ wk,
    const float* __restrict__ wr, const float* __restrict__ bias,
    const float* __restrict__ dk, const float* __restrict__ dbp,
    float* __restrict__ out, float* __restrict__ hbuf, float* __restrict__ pd)
{
    __shared__ __align__(16) float Wlds[8][1024];
    __shared__ float parts[8][128][9];
    __shared__ float c_state[128][2];
    __shared__ float ut_lds[128];
    __shared__ float bias_l[8];
    __shared__ float dk_l[4];
    __shared__ float db_l;

    const int tid = threadIdx.x;
    const int u0 = blockIdx.x * 2;

    #pragma unroll
    for (int c = 0; c < 8; ++c) {
        const int g = c >> 1, j = c & 1;
        const int gcol = g * U_ + u0 + j;
        Wlds[c][tid] = (tid < D_) ? wk[(size_t)tid * G4 + gcol]
                                  : wr[(size_t)(tid - D_) * G4 + gcol];
    }
    if (tid < 8)  bias_l[tid] = bias[(tid >> 1) * U_ + u0 + (tid & 1)];
    if (tid < 2) { dk_l[tid] = dk[u0 + tid]; dk_l[2 + tid] = dk[U_ + u0 + tid]; }
    if (tid == 0) db_l = dbp[0];
    if (tid < 128) { ut_lds[tid] = 1.0f; c_state[tid][0] = 0.0f; c_state[tid][1] = 0.0f; }
    if (tid < 512) hbuf[blockIdx.x * 512 + tid] = 0.0f;

    cg::grid_group grid = cg::this_grid();
    __syncthreads();
    grid.sync();

    const int b    = tid & 127;
    const int ksub = tid >> 7;

    #pragma unroll 1
    for (int t = 0; t < T_; ++t) {
        const float* __restrict__ hcur = hbuf + (t & 1) * (B_ * U_);
        float* __restrict__ hnxt = hbuf + ((t + 1) & 1) * (B_ * U_);

        const float* inp = (ksub < 4)
            ? (x + (size_t)b * (T_ * D_) + (size_t)t * D_ + ksub * 128)
            : (hcur + b * U_ + (ksub - 4) * 128);
        const float4* __restrict__ in4 = (const float4*)inp;
        const int kb4 = ksub * 32;

        float acc[8] = {0.f,0.f,0.f,0.f,0.f,0.f,0.f,0.f};
        #pragma unroll 1
        for (int l = 0; l < 8; ++l) {
            float4 v[4];
            #pragma unroll
            for (int m = 0; m < 4; ++m) v[m] = in4[l*4 + m];
            #pragma unroll
            for (int c = 0; c < 8; ++c) {
                const float4* wrow = (const float4*)(&Wlds[c][0]);
                #pragma unroll
                for (int m = 0; m < 4; ++m) {
                    const float4 w = wrow[kb4 + l*4 + m];
                    acc[c] += v[m].x*w.x + v[m].y*w.y + v[m].z*w.z + v[m].w*w.w;
                }
            }
        }
        #pragma unroll
        for (int c = 0; c < 8; ++c) parts[ksub][b][c] = acc[c];
        __syncthreads();

        if (tid < 256) {
            const int bb = tid >> 1, j = tid & 1;
            float z[4];
            #pragma unroll
            for (int g = 0; g < 4; ++g) {
                float s = bias_l[g*2 + j];
                #pragma unroll
                for (int ks = 0; ks < 8; ++ks) s += parts[ks][bb][g*2 + j];
                z[g] = s;
            }
            const float ut    = ut_lds[bb];
            const float ug    = rintf(ut);
            const float c_old = c_state[bb][j];
            const float si = sigm(z[0]);
            const float sf = sigm(z[1]);
            const float gg = tanhf(z[2]);
            const float so = sigm(z[3]);
            const float c_n = sf * c_old + si * gg;
            const float h_n = so * tanhf(c_n);
            const float h_old = hcur[bb * U_ + u0 + j];
            const float hbv = ug * h_old + (1.f - ug) * h_n;
            const float cbv = ug * c_old + (1.f - ug) * c_n;
            out[(size_t)bb * (T_ * U_) + (size_t)t * U_ + u0 + j] = h_n;
            hnxt[bb * U_ + u0 + j] = hbv;
            c_state[bb][j] = cbv;
            float p = hbv * dk_l[j] + cbv * dk_l[2 + j];
            p += __shfl_xor(p, 1);
            if (j == 0) pd[(t & 1) * (NBLK * B_) + blockIdx.x * B_ + bb] = p;
        }

        grid.sync();

        {
            const int bb2 = tid >> 3, o = tid & 7;
            const float* __restrict__ pdt = pd + (t & 1) * (NBLK * B_);
            float s = 0.f;
            #pragma unroll 1
            for (int i = 0; i < 32; ++i) s += pdt[(o * 32 + i) * B_ + bb2];
            s += __shfl_xor(s, 1);
            s += __shfl_xor(s, 2);
            s += __shfl_xor(s, 4);
            if (o == 0) {
                const float delta = sigm(s + db_l);
                const float ut = ut_lds[bb2];
                const float ug = rintf(ut);
                ut_lds[bb2] = ug * delta + (1.f - ug) * (ut + fminf(delta, 1.f - ut));
            }
        }
        __syncthreads();
    }
}

extern "C" void kernel_launch(void* const* d_in, const int* in_sizes, int n_in,
                              void* d_out, int out_size, void* d_ws, size_t ws_size,
                              hipStream_t stream)
{
    (void)in_sizes; (void)n_in; (void)out_size;
    const float* x  = (const float*)d_in[0];
    const float* wk = (const float*)d_in[1];
    const float* wr = (const float*)d_in[2];
    const float* bs = (const float*)d_in[3];
    const float* dk = (const float*)d_in[4];
    const float* db = (const float*)d_in[5];
    float* out = (float*)d_out;

    const size_t xT_elems = (size_t)T_ * D_ * B_;      // 67,108,864
    const size_t hT_elems = (size_t)2 * U_ * B_;       // 131,072
    const size_t pd_elems = (size_t)2 * NBLK * B_;     // 65,536
    const size_t need = (xT_elems + hT_elems + pd_elems) * sizeof(float);

    if (ws_size >= need) {
        float* xT   = (float*)d_ws;
        float* hbuf = xT + xT_elems;
        float* pd   = hbuf + hT_elems;
        transpose_x<<<dim3(T_ * 16 * 4), dim3(256), 0, stream>>>(x, xT);
        void* args[] = { (void*)&xT, (void*)&wk, (void*)&wr, (void*)&bs, (void*)&dk, (void*)&db,
                         (void*)&out, (void*)&hbuf, (void*)&pd };
        hipLaunchCooperativeKernel(reinterpret_cast<void*>(skiplstm_kernel_T),
                                   dim3(NBLK), dim3(NTHR), args, 0, stream);
    } else {
        float* hbuf = (float*)d_ws;
        float* pd   = hbuf + hT_elems;
        void* args[] = { (void*)&x, (void*)&wk, (void*)&wr, (void*)&bs, (void*)&dk, (void*)&db,
                         (void*)&out, (void*)&hbuf, (void*)&pd };
        hipLaunchCooperativeKernel(reinterpret_cast<void*>(skiplstm_fallback),
                                   dim3(NBLK), dim3(NTHR), args, 0, stream);
    }
}

// Round 3
// 22470.026 us; speedup vs baseline: 3.3065x; 2.4677x over previous
//
#include <hip/hip_runtime.h>
#include <hip/hip_fp16.h>
#include <hip/hip_cooperative_groups.h>

namespace cg = cooperative_groups;

constexpr int B_ = 128, T_ = 1024, D_ = 512, U_ = 512;
constexpr int NBLK = 256, NTHR = 1024;
constexpr int G4 = 4 * U_;   // 2048 gate columns

__device__ __forceinline__ float sigm(float v) { return 1.0f / (1.0f + expf(-v)); }

#define AGENT_LD(p)    __hip_atomic_load((p), __ATOMIC_RELAXED, __HIP_MEMORY_SCOPE_AGENT)
#define AGENT_ST(p, v) __hip_atomic_store((p), (v), __ATOMIC_RELAXED, __HIP_MEMORY_SCOPE_AGENT)

template <typename ZT> __device__ __forceinline__ ZT    to_zt(float v);
template <> __device__ __forceinline__ float  to_zt<float>(float v)  { return v; }
template <> __device__ __forceinline__ __half to_zt<__half>(float v) { return __float2half(v); }
__device__ __forceinline__ float from_zt(float v)  { return v; }
__device__ __forceinline__ float from_zt(__half v) { return __half2float(v); }

// ---------------- x[b][t][k] -> xT[t][k][b] (coalesced both sides) -----------------
__global__ __launch_bounds__(256) void transpose_x(const float* __restrict__ x,
                                                   float* __restrict__ xT)
{
    __shared__ float tile[32][33];
    const int tileId = blockIdx.x;          // 1024 t * 16 ktiles * 4 btiles
    const int bt = tileId & 3;
    const int kt = (tileId >> 2) & 15;
    const int t  = tileId >> 6;
    const int tx = threadIdx.x & 31;
    const int ty = threadIdx.x >> 5;        // 0..7
    #pragma unroll
    for (int r = 0; r < 4; ++r) {
        const int b = bt * 32 + ty + r * 8;
        const int k = kt * 32 + tx;
        tile[ty + r * 8][tx] = x[(size_t)b * (T_ * D_) + (size_t)t * D_ + k];
    }
    __syncthreads();
    #pragma unroll
    for (int r = 0; r < 4; ++r) {
        const int k = kt * 32 + ty + r * 8;
        const int b = bt * 32 + tx;
        xT[((size_t)t * D_ + k) * B_ + b] = tile[tx][ty + r * 8];
    }
}

// ---------------- pack W: Wpk[blk][k 0..1023][c 0..7]; k<512 from wk else wr -------
__global__ __launch_bounds__(1024) void pack_w(const float* __restrict__ wk,
                                               const float* __restrict__ wr,
                                               float* __restrict__ Wpk)
{
    const size_t idx = (size_t)blockIdx.x * 1024 + threadIdx.x;  // 2,097,152 total
    const int    c   = (int)(idx & 7);
    const size_t k   = (idx >> 3) & 1023;
    const int    blk = (int)(idx >> 13);
    const int    col = ((c >> 1) << 9) + blk * 2 + (c & 1);
    Wpk[idx] = (k < 512) ? wk[k * G4 + col] : wr[(k - 512) * G4 + col];
}

// ---------------- zx[t][c][b] = bias[c] + sum_k xT[t][k][b]*Wk[k][c] ---------------
// 256 blocks own 8 gate cols each; W via wave-uniform (scalar) loads; no syncs across blocks.
template <typename ZT>
__global__ __launch_bounds__(NTHR, 4) void zx_gemm(
    const float* __restrict__ xT, const float* __restrict__ Wpk,
    const float* __restrict__ bias, ZT* __restrict__ zx)
{
    __shared__ float parts[8][128][9];
    __shared__ float bias_l[8];
    const int tid = threadIdx.x, blk = blockIdx.x, u0 = blk * 2;
    if (tid < 8) bias_l[tid] = bias[(tid >> 1) * U_ + u0 + (tid & 1)];
    const int b = tid & 127, ksub = tid >> 7;
    const int ksub_u = __builtin_amdgcn_readfirstlane(ksub);
    const float* __restrict__ wp = Wpk + ((size_t)blk * 1024 + (size_t)ksub_u * 64) * 8;
    __syncthreads();

    for (int t = 0; t < T_; ++t) {
        const float* __restrict__ xp = xT + ((size_t)t * D_ + ksub * 64) * B_ + b;
        float acc[8] = {0.f,0.f,0.f,0.f,0.f,0.f,0.f,0.f};
        #pragma unroll 2
        for (int kq = 0; kq < 16; ++kq) {
            const float v0 = xp[(kq * 4 + 0) * B_];
            const float v1 = xp[(kq * 4 + 1) * B_];
            const float v2 = xp[(kq * 4 + 2) * B_];
            const float v3 = xp[(kq * 4 + 3) * B_];
            const float* __restrict__ w = wp + kq * 32;   // wave-uniform -> s_load
            #pragma unroll
            for (int c = 0; c < 8; ++c)
                acc[c] += v0 * w[c] + v1 * w[8 + c] + v2 * w[16 + c] + v3 * w[24 + c];
        }
        #pragma unroll
        for (int c = 0; c < 8; ++c) parts[ksub][b][c] = acc[c];
        __syncthreads();
        {
            const int c = tid >> 7, bb = tid & 127;   // 8 x 128 = 1024 outputs
            float s = bias_l[c];
            #pragma unroll
            for (int ks = 0; ks < 8; ++ks) s += parts[ks][bb][c];
            zx[((size_t)t * G4 + (c >> 1) * U_ + u0 + (c & 1)) * B_ + bb] = to_zt<ZT>(s);
        }
        __syncthreads();
    }
}

// ---------------- main recurrent loop ----------------------------------------------
// Per step: h@Wr (W via s_load, h via agent loads) -> parts reduce -> gates/blend ->
// custom grid barrier (monotonic counter, agent atomics; no L2 invalidate) -> delta.
template <typename ZT>
__global__ __launch_bounds__(NTHR, 4) void skiplstm_loop(
    const ZT* __restrict__ zx, const float* __restrict__ Wpk,
    const float* __restrict__ dk, const float* __restrict__ dbp,
    float* __restrict__ out, float* __restrict__ hbuf,
    float* __restrict__ pd, unsigned* __restrict__ bar)
{
    __shared__ float parts[8][128][9];
    __shared__ float pdpart[8][128];
    __shared__ float c_state[128][2];
    __shared__ float h_state[128][2];   // our block's hb from previous step
    __shared__ float ut_lds[128];
    __shared__ float dk_l[4];
    __shared__ float db_l;

    const int tid = threadIdx.x;
    const int blk = blockIdx.x;
    const int u0  = blk * 2;

    if (tid < 2) { dk_l[tid] = dk[u0 + tid]; dk_l[2 + tid] = dk[U_ + u0 + tid]; }
    if (tid == 0) db_l = dbp[0];
    if (tid < 128) {
        ut_lds[tid] = 1.0f;
        c_state[tid][0] = 0.f; c_state[tid][1] = 0.f;
        h_state[tid][0] = 0.f; h_state[tid][1] = 0.f;
    }
    __syncthreads();

    const int b    = tid & 127;
    const int ksub = tid >> 7;
    const int ksub_u = __builtin_amdgcn_readfirstlane(ksub);
    const float* __restrict__ wp = Wpk + ((size_t)blk * 1024 + 512 + (size_t)ksub_u * 64) * 8;

    unsigned tgt = 0;
    #pragma unroll 1
    for (int t = 0; t < T_; ++t) {
        const float* __restrict__ hcur = hbuf + (t & 1) * (U_ * B_);
        float* __restrict__ hnxt = hbuf + ((t + 1) & 1) * (U_ * B_);

        // ---- phase 1a: h @ Wr partials (h agent loads, W scalar loads) ----
        const float* __restrict__ hp = hcur + (size_t)(ksub * 64) * B_ + b;
        float acc[8] = {0.f,0.f,0.f,0.f,0.f,0.f,0.f,0.f};
        #pragma unroll 2
        for (int kq = 0; kq < 16; ++kq) {
            const float v0 = AGENT_LD(hp + (kq * 4 + 0) * B_);
            const float v1 = AGENT_LD(hp + (kq * 4 + 1) * B_);
            const float v2 = AGENT_LD(hp + (kq * 4 + 2) * B_);
            const float v3 = AGENT_LD(hp + (kq * 4 + 3) * B_);
            const float* __restrict__ w = wp + kq * 32;   // wave-uniform -> s_load
            #pragma unroll
            for (int c = 0; c < 8; ++c)
                acc[c] += v0 * w[c] + v1 * w[8 + c] + v2 * w[16 + c] + v3 * w[24 + c];
        }
        #pragma unroll
        for (int c = 0; c < 8; ++c) parts[ksub][b][c] = acc[c];
        __syncthreads();

        // ---- phase 1b: gates, blend, output, dense partial ----
        if (tid < 256) {
            const int bb = tid >> 1, j = tid & 1;
            float z[4];
            #pragma unroll
            for (int g = 0; g < 4; ++g) {
                float s = from_zt(zx[((size_t)t * G4 + g * U_ + u0 + j) * B_ + bb]);
                #pragma unroll
                for (int ks = 0; ks < 8; ++ks) s += parts[ks][bb][g * 2 + j];
                z[g] = s;
            }
            const float ut    = ut_lds[bb];
            const float ug    = rintf(ut);
            const float c_old = c_state[bb][j];
            const float si = sigm(z[0]);
            const float sf = sigm(z[1]);
            const float gg = tanhf(z[2]);
            const float so = sigm(z[3]);
            const float c_n = sf * c_old + si * gg;
            const float h_n = so * tanhf(c_n);
            const float h_old = h_state[bb][j];
            const float hbv = ug * h_old + (1.f - ug) * h_n;
            const float cbv = ug * c_old + (1.f - ug) * c_n;
            out[(size_t)bb * (T_ * U_) + (size_t)t * U_ + u0 + j] = h_n;
            AGENT_ST(hnxt + (size_t)(u0 + j) * B_ + bb, hbv);
            c_state[bb][j] = cbv;
            h_state[bb][j] = hbv;
            float p = hbv * dk_l[j] + cbv * dk_l[2 + j];
            p += __shfl_xor(p, 1);
            if (j == 0) AGENT_ST(pd + (t & 1) * (NBLK * B_) + blk * B_ + bb, p);
        }
        __syncthreads();   // each wave drains its vmem (incl. agent stores) before arrive

        // ---- custom grid barrier: monotonic counter, no cache flush ----
        tgt += NBLK;
        if (tid == 0) {
            __hip_atomic_fetch_add(bar, 1u, __ATOMIC_RELAXED, __HIP_MEMORY_SCOPE_AGENT);
            while (__hip_atomic_load(bar, __ATOMIC_RELAXED, __HIP_MEMORY_SCOPE_AGENT) < tgt)
                __builtin_amdgcn_s_sleep(2);
        }
        __syncthreads();

        // ---- phase 2: redundant delta reduce (coalesced), update private ut ----
        {
            const int o2  = tid >> 7;     // wave-uniform
            const int bb2 = tid & 127;    // lane dim -> coalesced
            const float* __restrict__ pdt = pd + (t & 1) * (NBLK * B_);
            float s = 0.f;
            #pragma unroll 4
            for (int i = 0; i < 32; ++i)
                s += AGENT_LD(pdt + (size_t)(o2 * 32 + i) * B_ + bb2);
            pdpart[o2][bb2] = s;
        }
        __syncthreads();
        if (tid < 128) {
            float ss = 0.f;
            #pragma unroll
            for (int o = 0; o < 8; ++o) ss += pdpart[o][tid];
            const float delta = sigm(ss + db_l);
            const float ut = ut_lds[tid];
            const float ug = rintf(ut);
            ut_lds[tid] = ug * delta + (1.f - ug) * (ut + fminf(delta, 1.f - ut));
        }
        // no trailing sync needed: next step's parts __syncthreads orders ut_lds use
    }
}

// ---------------- R2 fallback (ws too small): proven 55 ms path --------------------
__global__ __launch_bounds__(NTHR, 4) void skiplstm_kernel_T(
    const float* __restrict__ xT, const float* __restrict__ wk,
    const float* __restrict__ wr, const float* __restrict__ bias,
    const float* __restrict__ dk, const float* __restrict__ dbp,
    float* __restrict__ out, float* __restrict__ hbuf, float* __restrict__ pd)
{
    __shared__ __align__(16) float Wlds[8][1024];
    __shared__ float parts[8][128][9];
    __shared__ float c_state[128][2];
    __shared__ float ut_lds[128];
    __shared__ float bias_l[8];
    __shared__ float dk_l[4];
    __shared__ float db_l;

    const int tid = threadIdx.x;
    const int u0 = blockIdx.x * 2;

    #pragma unroll
    for (int c = 0; c < 8; ++c) {
        const int g = c >> 1, j = c & 1;
        const int gcol = g * U_ + u0 + j;
        Wlds[c][tid] = (tid < D_) ? wk[(size_t)tid * G4 + gcol]
                                  : wr[(size_t)(tid - D_) * G4 + gcol];
    }
    if (tid < 8)  bias_l[tid] = bias[(tid >> 1) * U_ + u0 + (tid & 1)];
    if (tid < 2) { dk_l[tid] = dk[u0 + tid]; dk_l[2 + tid] = dk[U_ + u0 + tid]; }
    if (tid == 0) db_l = dbp[0];
    if (tid < 128) { ut_lds[tid] = 1.0f; c_state[tid][0] = 0.0f; c_state[tid][1] = 0.0f; }
    if (tid < 512) hbuf[blockIdx.x * 512 + tid] = 0.0f;

    cg::grid_group grid = cg::this_grid();
    __syncthreads();
    grid.sync();

    const int b    = tid & 127;
    const int ksub = tid >> 7;

    #pragma unroll 1
    for (int t = 0; t < T_; ++t) {
        const float* __restrict__ hcurT = hbuf + (t & 1) * (U_ * B_);
        float* __restrict__ hnxtT = hbuf + ((t + 1) & 1) * (U_ * B_);

        const float* __restrict__ src = (ksub < 4)
            ? (xT + ((size_t)t * D_ + ksub * 128) * B_ + b)
            : (hcurT + (size_t)(ksub - 4) * 128 * B_ + b);

        float acc[8] = {0.f,0.f,0.f,0.f,0.f,0.f,0.f,0.f};
        #pragma unroll 2
        for (int kq = 0; kq < 32; ++kq) {
            const float v0 = src[(kq * 4 + 0) * B_];
            const float v1 = src[(kq * 4 + 1) * B_];
            const float v2 = src[(kq * 4 + 2) * B_];
            const float v3 = src[(kq * 4 + 3) * B_];
            const int k4 = ksub * 32 + kq;
            #pragma unroll
            for (int c = 0; c < 8; ++c) {
                const float4 w = ((const float4*)(&Wlds[c][0]))[k4];
                acc[c] += v0 * w.x + v1 * w.y + v2 * w.z + v3 * w.w;
            }
        }
        #pragma unroll
        for (int c = 0; c < 8; ++c) parts[ksub][b][c] = acc[c];
        __syncthreads();

        if (tid < 256) {
            const int bb = tid >> 1, j = tid & 1;
            float z[4];
            #pragma unroll
            for (int g = 0; g < 4; ++g) {
                float s = bias_l[g*2 + j];
                #pragma unroll
                for (int ks = 0; ks < 8; ++ks) s += parts[ks][bb][g*2 + j];
                z[g] = s;
            }
            const float ut    = ut_lds[bb];
            const float ug    = rintf(ut);
            const float c_old = c_state[bb][j];
            const float si = sigm(z[0]);
            const float sf = sigm(z[1]);
            const float gg = tanhf(z[2]);
            const float so = sigm(z[3]);
            const float c_n = sf * c_old + si * gg;
            const float h_n = so * tanhf(c_n);
            const float h_old = hcurT[(u0 + j) * B_ + bb];
            const float hbv = ug * h_old + (1.f - ug) * h_n;
            const float cbv = ug * c_old + (1.f - ug) * c_n;
            out[(size_t)bb * (T_ * U_) + (size_t)t * U_ + u0 + j] = h_n;
            hnxtT[(u0 + j) * B_ + bb] = hbv;
            c_state[bb][j] = cbv;
            float p = hbv * dk_l[j] + cbv * dk_l[2 + j];
            p += __shfl_xor(p, 1);
            if (j == 0) pd[(t & 1) * (NBLK * B_) + blockIdx.x * B_ + bb] = p;
        }

        grid.sync();

        {
            const int bb2 = tid >> 3, o = tid & 7;
            const float* __restrict__ pdt = pd + (t & 1) * (NBLK * B_);
            float s = 0.f;
            #pragma unroll 1
            for (int i = 0; i < 32; ++i) s += pdt[(o * 32 + i) * B_ + bb2];
            s += __shfl_xor(s, 1);
            s += __shfl_xor(s, 2);
            s += __shfl_xor(s, 4);
            if (o == 0) {
                const float delta = sigm(s + db_l);
                const float ut = ut_lds[bb2];
                const float ug = rintf(ut);
                ut_lds[bb2] = ug * delta + (1.f - ug) * (ut + fminf(delta, 1.f - ut));
            }
        }
        __syncthreads();
    }
}

// ---------------- host ----------------------------------------------------------
extern "C" void kernel_launch(void* const* d_in, const int* in_sizes, int n_in,
                              void* d_out, int out_size, void* d_ws, size_t ws_size,
                              hipStream_t stream)
{
    (void)in_sizes; (void)n_in; (void)out_size;
    const float* x  = (const float*)d_in[0];
    const float* wk = (const float*)d_in[1];
    const float* wr = (const float*)d_in[2];
    const float* bs = (const float*)d_in[3];
    const float* dk = (const float*)d_in[4];
    const float* db = (const float*)d_in[5];
    float* out = (float*)d_out;

    const size_t xT_b   = (size_t)T_ * D_ * B_ * 4;          // 256 MiB
    const size_t wpk_b  = (size_t)NBLK * 1024 * 8 * 4;       // 8 MiB
    const size_t hbuf_b = (size_t)2 * U_ * B_ * 4;           // 512 KiB
    const size_t pd_b   = (size_t)2 * NBLK * B_ * 4;         // 256 KiB
    const size_t zx32_b = (size_t)T_ * G4 * B_ * 4;          // 1 GiB
    const size_t zx16_b = zx32_b / 2;                        // 512 MiB
    const size_t tail_b = hbuf_b + pd_b + 256;

    const size_t need_A = zx32_b + xT_b + wpk_b + tail_b;
    const size_t need_B = zx16_b + xT_b + wpk_b + tail_b;
    const size_t need_C = xT_b + hbuf_b + pd_b;

    char* w = (char*)d_ws;

    if (ws_size >= need_B) {
        const bool f32zx = (ws_size >= need_A);
        const size_t zx_b = f32zx ? zx32_b : zx16_b;
        char* zxp  = w;
        float* xT  = (float*)(w + zx_b);
        float* Wpk = (float*)(w + zx_b + xT_b);
        float* hbuf = (float*)(w + zx_b + xT_b + wpk_b);
        float* pd   = (float*)(w + zx_b + xT_b + wpk_b + hbuf_b);
        unsigned* bar = (unsigned*)(w + zx_b + xT_b + wpk_b + hbuf_b + pd_b);

        // zero h buffers + pd + barrier counter (one contiguous region)
        hipMemsetAsync(hbuf, 0, hbuf_b + pd_b + 256, stream);
        transpose_x<<<dim3(T_ * 16 * 4), dim3(256), 0, stream>>>(x, xT);
        pack_w<<<dim3(2048), dim3(1024), 0, stream>>>(wk, wr, Wpk);

        if (f32zx) {
            float* zx = (float*)zxp;
            zx_gemm<float><<<dim3(NBLK), dim3(NTHR), 0, stream>>>(xT, Wpk, bs, zx);
            void* args[] = { (void*)&zx, (void*)&Wpk, (void*)&dk, (void*)&db,
                             (void*)&out, (void*)&hbuf, (void*)&pd, (void*)&bar };
            hipLaunchCooperativeKernel(reinterpret_cast<void*>(skiplstm_loop<float>),
                                       dim3(NBLK), dim3(NTHR), args, 0, stream);
        } else {
            __half* zx = (__half*)zxp;
            zx_gemm<__half><<<dim3(NBLK), dim3(NTHR), 0, stream>>>(xT, Wpk, bs, zx);
            void* args[] = { (void*)&zx, (void*)&Wpk, (void*)&dk, (void*)&db,
                             (void*)&out, (void*)&hbuf, (void*)&pd, (void*)&bar };
            hipLaunchCooperativeKernel(reinterpret_cast<void*>(skiplstm_loop<__half>),
                                       dim3(NBLK), dim3(NTHR), args, 0, stream);
        }
    } else {
        // R2 fallback
        float* xT   = (float*)d_ws;
        float* hbuf = xT + (size_t)T_ * D_ * B_;
        float* pd   = hbuf + 2 * U_ * B_;
        transpose_x<<<dim3(T_ * 16 * 4), dim3(256), 0, stream>>>(x, xT);
        void* args[] = { (void*)&xT, (void*)&wk, (void*)&wr, (void*)&bs, (void*)&dk, (void*)&db,
                         (void*)&out, (void*)&hbuf, (void*)&pd };
        hipLaunchCooperativeKernel(reinterpret_cast<void*>(skiplstm_kernel_T),
                                   dim3(NBLK), dim3(NTHR), args, 0, stream);
        (void)need_C;
    }
}